// Round 1
// baseline (356.177 us; speedup 1.0000x reference)
//
#include <hip/hip_runtime.h>
#include <hip/hip_bf16.h>

// Causal flash attention forward. B=2,H=16,S=2048,D=128, fp32 in/out,
// bf16 MFMA internally (threshold 7.7e-2 is bf16-class).
constexpr int Bb = 2, Hh = 16, Ss = 2048, Dd = 128;
constexpr int BM = 64, BN = 64;
constexpr int NQT = Ss / BM;          // 32 q-tiles per (b,h)
constexpr float SCALE = 0.088388347648318447f;   // 1/sqrt(128)

typedef __attribute__((ext_vector_type(8))) short bf16x8;
typedef __attribute__((ext_vector_type(4))) short short4v;
typedef __attribute__((ext_vector_type(4))) float f32x4;

__device__ __forceinline__ short f2bf(float f) {
  union { float f; unsigned u; } v; v.f = f;
  unsigned r = (v.u + 0x7FFFu + ((v.u >> 16) & 1u)) >> 16;   // RNE
  return (short)r;
}

__global__ __launch_bounds__(256, 2)
void fa_fwd_kernel(const float* __restrict__ q,
                   const float* __restrict__ k,
                   const float* __restrict__ v,
                   float* __restrict__ out) {
  // K tile: row-major bf16, row = 256 B (16 x 16B blocks), swizzle block^(row&15)
  __shared__ __align__(16) char Klds[BN * 256];      // 16 KB
  // V tile transposed: Vt[d][key], row = 128 B (8 x 16B blocks), swizzle block^(d&7)
  __shared__ __align__(16) char Vt[Dd * 128];        // 16 KB
  // P round-trip (C-layout -> A-layout), per-wave 16x64 fp32, stride 68 dwords
  __shared__ __align__(16) float Plds[4 * 16 * 68];  // 17 KB

  const int tid  = threadIdx.x;
  const int wave = tid >> 6;
  const int lane = tid & 63;
  const int quad = lane >> 4;
  const int l16  = lane & 15;

  const int bid = blockIdx.x;
  const int bh  = bid & 31;                 // B*H = 32
  const int qt  = (NQT - 1) - (bid >> 5);   // heavy tiles first

  const float* qb = q + (size_t)bh * Ss * Dd;
  const float* kb = k + (size_t)bh * Ss * Dd;
  const float* vb = v + (size_t)bh * Ss * Dd;

  // ---- Q fragments (A operand), scale folded in. 4 k-steps of 32.
  bf16x8 qf[4];
  {
    const float* qr = qb + (size_t)(qt * BM + wave * 16 + l16) * Dd + quad * 8;
    #pragma unroll
    for (int ks = 0; ks < 4; ++ks) {
      const float* p = qr + ks * 32;
      float4 a = *(const float4*)p;
      float4 b = *(const float4*)(p + 4);
      bf16x8 t;
      t[0] = f2bf(a.x * SCALE); t[1] = f2bf(a.y * SCALE);
      t[2] = f2bf(a.z * SCALE); t[3] = f2bf(a.w * SCALE);
      t[4] = f2bf(b.x * SCALE); t[5] = f2bf(b.y * SCALE);
      t[6] = f2bf(b.z * SCALE); t[7] = f2bf(b.w * SCALE);
      qf[ks] = t;
    }
  }

  f32x4 o[8];
  #pragma unroll
  for (int i = 0; i < 8; ++i) o[i] = (f32x4)(0.0f);
  float mrow[4], lrow[4];
  #pragma unroll
  for (int r = 0; r < 4; ++r) { mrow[r] = -3.0e38f; lrow[r] = 0.0f; }

  float* Pw = Plds + wave * 16 * 68;

  for (int kt = 0; kt <= qt; ++kt) {
    __syncthreads();   // previous iteration's readers done before restaging

    // ---- stage K tile: fp32 -> bf16, row-major, swizzled
    {
      const float* Kg = kb + (size_t)(kt * BN) * Dd;
      #pragma unroll
      for (int i = 0; i < 8; ++i) {
        int idx = tid + i * 256;         // float4 index
        int key = idx >> 5;              // /(128/4)
        int d0  = (idx & 31) << 2;
        float4 f = *(const float4*)(Kg + key * Dd + d0);
        int block = d0 >> 3;             // 16B block
        int off   = (d0 & 4) << 1;       // byte offset within block
        int bswz  = block ^ (key & 15);
        short4v h = { f2bf(f.x), f2bf(f.y), f2bf(f.z), f2bf(f.w) };
        *(short4v*)(Klds + key * 256 + bswz * 16 + off) = h;
      }
    }
    // ---- stage V tile transposed: Vt[d][key], swizzled
    {
      const float* Vg = vb + (size_t)(kt * BN) * Dd;
      #pragma unroll
      for (int i = 0; i < 2; ++i) {
        int u  = tid + i * 256;          // unit: (key-quad, d-quad)
        int dq = u & 31, kq = u >> 5;    // kq 0..15
        int d0 = dq * 4, k0 = kq * 4;
        float4 r0 = *(const float4*)(Vg + (size_t)(k0 + 0) * Dd + d0);
        float4 r1 = *(const float4*)(Vg + (size_t)(k0 + 1) * Dd + d0);
        float4 r2 = *(const float4*)(Vg + (size_t)(k0 + 2) * Dd + d0);
        float4 r3 = *(const float4*)(Vg + (size_t)(k0 + 3) * Dd + d0);
        float a0[4] = {r0.x, r0.y, r0.z, r0.w};
        float a1[4] = {r1.x, r1.y, r1.z, r1.w};
        float a2[4] = {r2.x, r2.y, r2.z, r2.w};
        float a3[4] = {r3.x, r3.y, r3.z, r3.w};
        int block = k0 >> 3;
        int off   = (k0 & 4) << 1;
        #pragma unroll
        for (int j = 0; j < 4; ++j) {
          int d = d0 + j;
          int bswz = block ^ (d & 7);
          short4v h = { f2bf(a0[j]), f2bf(a1[j]), f2bf(a2[j]), f2bf(a3[j]) };
          *(short4v*)(Vt + d * 128 + bswz * 16 + off) = h;
        }
      }
    }
    __syncthreads();

    // ---- S = Q K^T : per-wave 16x64, 4 n-tiles x 4 k-steps
    f32x4 acc[4];
    #pragma unroll
    for (int nt = 0; nt < 4; ++nt) acc[nt] = (f32x4)(0.0f);
    #pragma unroll
    for (int ks = 0; ks < 4; ++ks) {
      #pragma unroll
      for (int nt = 0; nt < 4; ++nt) {
        int row  = nt * 16 + l16;
        int bswz = (ks * 4 + quad) ^ l16;
        bf16x8 kf = *(const bf16x8*)(Klds + row * 256 + bswz * 16);
        acc[nt] = __builtin_amdgcn_mfma_f32_16x16x32_bf16(qf[ks], kf, acc[nt], 0, 0, 0);
      }
    }

    // ---- causal mask on diagonal tile
    if (kt == qt) {
      #pragma unroll
      for (int nt = 0; nt < 4; ++nt) {
        int kcol = nt * 16 + l16;
        #pragma unroll
        for (int r = 0; r < 4; ++r) {
          int qrow = wave * 16 + quad * 4 + r;
          if (kcol > qrow) acc[nt][r] = -1.0e30f;
        }
      }
    }

    // ---- online softmax: row max (16-lane butterfly within each quad)
    float mx[4];
    #pragma unroll
    for (int r = 0; r < 4; ++r) {
      float m0 = fmaxf(fmaxf(acc[0][r], acc[1][r]), fmaxf(acc[2][r], acc[3][r]));
      m0 = fmaxf(m0, __shfl_xor(m0, 1, 64));
      m0 = fmaxf(m0, __shfl_xor(m0, 2, 64));
      m0 = fmaxf(m0, __shfl_xor(m0, 4, 64));
      m0 = fmaxf(m0, __shfl_xor(m0, 8, 64));
      mx[r] = m0;
    }
    float alpha[4];
    #pragma unroll
    for (int r = 0; r < 4; ++r) {
      float mn = fmaxf(mrow[r], mx[r]);
      alpha[r] = __expf(mrow[r] - mn);
      mrow[r] = mn;
    }
    float rs[4] = {0.f, 0.f, 0.f, 0.f};
    #pragma unroll
    for (int nt = 0; nt < 4; ++nt) {
      #pragma unroll
      for (int r = 0; r < 4; ++r) {
        float pv = __expf(acc[nt][r] - mrow[r]);
        acc[nt][r] = pv;
        rs[r] += pv;
      }
    }
    #pragma unroll
    for (int r = 0; r < 4; ++r) {
      float s = rs[r];
      s += __shfl_xor(s, 1, 64);
      s += __shfl_xor(s, 2, 64);
      s += __shfl_xor(s, 4, 64);
      s += __shfl_xor(s, 8, 64);
      lrow[r] = lrow[r] * alpha[r] + s;
    }
    #pragma unroll
    for (int dt = 0; dt < 8; ++dt) {
      #pragma unroll
      for (int r = 0; r < 4; ++r) o[dt][r] *= alpha[r];
    }

    // ---- P: C-layout -> A-layout via wave-private LDS (no barrier needed)
    #pragma unroll
    for (int nt = 0; nt < 4; ++nt) {
      #pragma unroll
      for (int r = 0; r < 4; ++r)
        Pw[(quad * 4 + r) * 68 + nt * 16 + l16] = acc[nt][r];
    }
    bf16x8 pf[2];
    #pragma unroll
    for (int ks2 = 0; ks2 < 2; ++ks2) {
      const float* pr = Pw + l16 * 68 + ks2 * 32 + quad * 8;
      float4 a = *(const float4*)pr;
      float4 b = *(const float4*)(pr + 4);
      bf16x8 t;
      t[0] = f2bf(a.x); t[1] = f2bf(a.y); t[2] = f2bf(a.z); t[3] = f2bf(a.w);
      t[4] = f2bf(b.x); t[5] = f2bf(b.y); t[6] = f2bf(b.z); t[7] = f2bf(b.w);
      pf[ks2] = t;
    }

    // ---- O += P V : 8 d-tiles x 2 k-steps
    #pragma unroll
    for (int ks2 = 0; ks2 < 2; ++ks2) {
      #pragma unroll
      for (int dt = 0; dt < 8; ++dt) {
        int row  = dt * 16 + l16;
        int bswz = (ks2 * 4 + quad) ^ (row & 7);
        bf16x8 vf = *(const bf16x8*)(Vt + row * 128 + bswz * 16);
        o[dt] = __builtin_amdgcn_mfma_f32_16x16x32_bf16(pf[ks2], vf, o[dt], 0, 0, 0);
      }
    }
  }

  // ---- epilogue: O / l
  float inv[4];
  #pragma unroll
  for (int r = 0; r < 4; ++r) inv[r] = 1.0f / lrow[r];
  float* ob = out + ((size_t)bh * Ss + qt * BM + wave * 16) * Dd;
  #pragma unroll
  for (int dt = 0; dt < 8; ++dt) {
    #pragma unroll
    for (int r = 0; r < 4; ++r)
      ob[(quad * 4 + r) * Dd + dt * 16 + l16] = o[dt][r] * inv[r];
  }
}

extern "C" void kernel_launch(void* const* d_in, const int* in_sizes, int n_in,
                              void* d_out, int out_size, void* d_ws, size_t ws_size,
                              hipStream_t stream) {
  const float* q = (const float*)d_in[0];
  const float* k = (const float*)d_in[1];
  const float* v = (const float*)d_in[2];
  float* out = (float*)d_out;
  dim3 grid(Bb * Hh * NQT);   // 1024 blocks
  dim3 block(256);
  hipLaunchKernelGGL(fa_fwd_kernel, grid, block, 0, stream, q, k, v, out);
}